// Round 16
// baseline (121.487 us; speedup 1.0000x reference)
//
#include <hip/hip_runtime.h>

#define B_ 8
#define N_ 4096
#define F_ 512

typedef __attribute__((ext_vector_type(8))) short bf16x8;
typedef __attribute__((ext_vector_type(4))) float f32x4;

#define XPAD 524   // u16 row stride: 262 dw == 6 mod 32 -> distinct lane banks; 8B-aligned

// S (512 x 64) = [left | right | left_local | right_local], each [512][16] row-major.
__device__ __forceinline__ float Sval(const float* l, const float* r,
                                      const float* ll, const float* rl,
                                      int h, int e) {
    const int m = e >> 4, c = e & 15;
    const float* p = (m == 0) ? l : (m == 1) ? r : (m == 2) ? ll : rl;
    return p[h * 16 + c];
}

__device__ __forceinline__ float qval(const float* coeff, const float* coeff_l,
                                      int b, int j) {
    if (j < 16) return 1.f;
    if (j < 32) return coeff[b * 16 + (j - 16)];
    if (j < 48) return 1.f;
    return coeff_l[b * 16 + (j - 48)];
}

__device__ __forceinline__ float lane_bcast(float v, int lane) {
    return __int_as_float(__builtin_amdgcn_readlane(__float_as_int(v), lane));
}

__device__ __forceinline__ unsigned short bf16_rn(float x) {
    unsigned u = __float_as_uint(x);
    unsigned r = u + 0x7FFFu + ((u >> 16) & 1u);
    return (unsigned short)(r >> 16);
}

// split x ~= hi + lo, both bf16 (error ~2^-17 |x|)
__device__ __forceinline__ void bf16_split(float x, short& hi, short& lo) {
    const unsigned short h = bf16_rn(x);
    const float hf = __uint_as_float(((unsigned)h) << 16);
    const unsigned short s = bf16_rn(x - hf);
    hi = (short)h; lo = (short)s;
}

__device__ __forceinline__ float b2f(unsigned short u) {
    return __uint_as_float(((unsigned)u) << 16);
}

// ---- k_prep: GS row i + S-fragment f2=i for phase-2 B-operand. grid 64.
__global__ __launch_bounds__(256) void k_prep(const float* l, const float* r,
                                              const float* ll, const float* rl,
                                              float* GS, unsigned short* Sf) {
    __shared__ float red[4][64];
    const int i = blockIdx.x;
    const int t = threadIdx.x;
    const int j = t & 63, seg = t >> 6;

    {
        const int ht = i >> 1, eh = i & 1;
        for (int idx = t; idx < 512; idx += 256) {
            const int lx = idx >> 3, ii = idx & 7;
            const int h = ht * 16 + (lx & 15);
            const int e = eh * 32 + ((lx >> 4) & 3) * 8 + ii;
            short hh, ss;
            bf16_split(Sval(l, r, ll, rl, h, e), hh, ss);
            Sf[(i * 2 + 0) * 512 + idx] = (unsigned short)hh;
            Sf[(i * 2 + 1) * 512 + idx] = (unsigned short)ss;
        }
    }

    float acc = 0.f;
    const int h0 = seg * 128;
    for (int h = h0; h < h0 + 128; ++h)
        acc += Sval(l, r, ll, rl, h, i) * Sval(l, r, ll, rl, h, j);
    red[seg][j] = acc;
    __syncthreads();
    if (t < 64) GS[i * 64 + t] = red[0][t] + red[1][t] + red[2][t] + red[3][t];
}

// ---- k_solve: per-batch fused {build M/CP -> 4-wave blocked GJ -> Newton -> E ->
// SE -> SEf emission}, one phase-overlaid LDS. grid 8 (one block/b).
// Regions (floats):
//  @0     GST -> Tds
//  @4096  CPs -> Es                       (Es LIVE through phase 8!)
//  @8192  ABs -> Ms -> Tas -> SEs(4160)   (R14 BUG: SEs@0 spanned [0,4160) and
//  @12288 Ks ; Ss@12352(4224)              clobbered Es[0][0..63] at @4096 — fixed)
//  @16384 akp(512, GJ only) | @16896 u1/u2(64)
__global__ __launch_bounds__(256) void k_solve(const float* coeff, const float* gate,
                                               const float* coeff_l, const float* gate_l,
                                               const float* comm, const float* GSg,
                                               const float* l, const float* r,
                                               const float* ll, const float* rl,
                                               unsigned short* SEf) {
    __shared__ float smem[17024];
    float* GST = smem;          // -> Tds
    float* CPs = smem + 4096;   // -> Es
    float* ABs = smem + 8192;   // -> Ms -> Tas -> SEs
    float* Ms  = smem + 8192;
    float* Ks  = smem + 12288;
    float* Tds = smem;
    float* Tas = smem + 8192;
    float* Es  = smem + 4096;
    float* SEs = smem + 8192;   // phase 8, stride 65 (4160f) [8192,12352)
    float* Ss  = smem + 12352;  // phase 8, stride 66 (4224f) [12352,16576)
    float* akp_lds = smem + 16384;
    float* u1s = smem + 16896;
    float* u2s = smem + 16928;

    const int b = blockIdx.x, t = threadIdx.x;
    const int tx = t & 15, ty = t >> 4;
    const float g = gate[b], gl = gate_l[b];
    const float cs = comm[b] / 12.0f;

    // (1) u1/u2 + GST
    if (t < 32) {
        u1s[t] = (t < 16) ? g * coeff[b * 16 + t] : -g;
        u2s[t] = (t < 16) ? gl * coeff_l[b * 16 + t] : -gl;
    }
    for (int idx = t; idx < 4096; idx += 256) {
        const int i = idx & 63, e = idx >> 6;
        GST[idx] = -0.5f * qval(coeff, coeff_l, b, i) * GSg[(i ^ 16) * 64 + e];
    }
    __syncthreads();

    // (2) ABs
    for (int idx = t; idx < 2048; idx += 256) {
        const int which = idx >> 10;
        const int i = (idx >> 5) & 31, j = idx & 31;
        float val;
        if (which == 0) {
            const int v2i = (i < 16) ? 48 + i : 16 + i;
            const float v2sc = (i < 16) ? 1.f : coeff_l[b * 16 + (i - 16)];
            val = v2sc * u1s[j] * GSg[v2i * 64 + j];
        } else {
            const int v1i = (i < 16) ? 16 + i : i - 16;
            const float v1sc = (i < 16) ? 1.f : coeff[b * 16 + (i - 16)];
            val = v1sc * u2s[j] * GSg[v1i * 64 + 32 + j];
        }
        ABs[idx] = val;
    }
    __syncthreads();

    // (3) CP
    for (int idx = t; idx < 4096; idx += 256) {
        const int e = idx >> 6, j = idx & 63;
        float val = 0.f;
        if (j < 32) {
            if (e == j) val += 0.5f * u1s[j];
            if (e >= 32) val += cs * u2s[e - 32] * ABs[(e - 32) * 32 + j];
        } else {
            const int jp = j - 32;
            if (e == 32 + jp) val += 0.5f * u2s[jp];
            if (e < 32) val -= cs * u1s[e] * ABs[1024 + e * 32 + jp];
        }
        CPs[idx] = val;
    }
    __syncthreads();   // ABs readers done

    // (4) M = I + GST^T*CP
    {
        const int i0 = ty * 4, m0 = tx * 4;
        float acc[4][4];
#pragma unroll
        for (int i = 0; i < 4; ++i)
#pragma unroll
            for (int j = 0; j < 4; ++j) acc[i][j] = 0.f;
        for (int e = 0; e < 64; ++e) {
            const float4 av = *reinterpret_cast<const float4*>(&GST[e * 64 + i0]);
            const float4 bv = *reinterpret_cast<const float4*>(&CPs[e * 64 + m0]);
            const float a[4] = {av.x, av.y, av.z, av.w};
            const float bb[4] = {bv.x, bv.y, bv.z, bv.w};
#pragma unroll
            for (int i = 0; i < 4; ++i)
#pragma unroll
                for (int j = 0; j < 4; ++j) acc[i][j] += a[i] * bb[j];
        }
#pragma unroll
        for (int i = 0; i < 4; ++i)
#pragma unroll
            for (int j = 0; j < 4; ++j)
                Ms[(i0 + i) * 64 + m0 + j] =
                    acc[i][j] + (((i0 + i) == (m0 + j)) ? 1.f : 0.f);
    }
    __syncthreads();

    // (5) 4-wave blocked Gauss-Jordan: Ms -> Ks. Wave w owns rows 16w..16w+15
    // (a[16]/lane, static idx). 8 column-panels; owning wave runs the 8 in-panel
    // steps (same akp capture points as the R12-verified blocked GJ) and
    // publishes akp[8][64] via LDS; trailing rows are untouched during in-panel
    // so reading their multipliers at trailing time == the R12 snapshot.
    {
        const int wv = t >> 6, ln = t & 63;
        float a[16];
#pragma unroll
        for (int i = 0; i < 16; ++i) a[i] = Ms[(wv * 16 + i) * 64 + ln];
#pragma unroll
        for (int G = 0; G < 8; ++G) {
            __syncthreads();   // prev akp readers done / buffer free
            float akpr[8];
            const int ow = G >> 1;
            if (wv == ow) {
#pragma unroll
                for (int J = 0; J < 8; ++J) {
                    const int Bq = (G & 1) * 8;
                    const float dk = lane_bcast(a[Bq + J], 8 * G + J);
                    const float pinv = 1.0f / dk;
                    a[Bq + J] = (ln == 8 * G + J) ? pinv : a[Bq + J] * pinv;
                    akpr[J] = a[Bq + J] + ((ln == 8 * G + J) ? 1.0f : 0.0f);
                    akp_lds[J * 64 + ln] = akpr[J];
#pragma unroll
                    for (int I = 0; I < 8; ++I) {
                        if (I != J) {
                            const float f = lane_bcast(a[Bq + I], 8 * G + J);
                            a[Bq + I] = __builtin_fmaf(-f, akpr[J], a[Bq + I]);
                        }
                    }
                }
            }
            __syncthreads();
            if (wv != ow) {
#pragma unroll
                for (int j = 0; j < 8; ++j) akpr[j] = akp_lds[j * 64 + ln];
            }
#pragma unroll
            for (int i = 0; i < 16; ++i) {
                if (((wv * 16 + i) >> 3) != G) {
                    const float f0 = lane_bcast(a[i], 8 * G + 0);
                    const float f1 = lane_bcast(a[i], 8 * G + 1);
                    const float f2 = lane_bcast(a[i], 8 * G + 2);
                    const float f3 = lane_bcast(a[i], 8 * G + 3);
                    const float f4 = lane_bcast(a[i], 8 * G + 4);
                    const float f5 = lane_bcast(a[i], 8 * G + 5);
                    const float f6 = lane_bcast(a[i], 8 * G + 6);
                    const float f7 = lane_bcast(a[i], 8 * G + 7);
                    a[i] = __builtin_fmaf(-f0, akpr[0], a[i]);
                    a[i] = __builtin_fmaf(-f1, akpr[1], a[i]);
                    a[i] = __builtin_fmaf(-f2, akpr[2], a[i]);
                    a[i] = __builtin_fmaf(-f3, akpr[3], a[i]);
                    a[i] = __builtin_fmaf(-f4, akpr[4], a[i]);
                    a[i] = __builtin_fmaf(-f5, akpr[5], a[i]);
                    a[i] = __builtin_fmaf(-f6, akpr[6], a[i]);
                    a[i] = __builtin_fmaf(-f7, akpr[7], a[i]);
                }
            }
        }
#pragma unroll
        for (int i = 0; i < 16; ++i) Ks[(wv * 16 + i) * 64 + ln] = a[i];
    }
    __syncthreads();

    // (6) Td = CP*K -> @0 (GST dead) ; Ta = M*K -> @8192 (after barrier)
    {
        const int i0 = ty * 4, j0 = tx * 4;
        float accd[4][4], acca[4][4];
#pragma unroll
        for (int i = 0; i < 4; ++i)
#pragma unroll
            for (int j = 0; j < 4; ++j) { accd[i][j] = 0.f; acca[i][j] = 0.f; }
        for (int q = 0; q < 64; ++q) {
            const float4 bv = *reinterpret_cast<const float4*>(&Ks[q * 64 + j0]);
            const float bb[4] = {bv.x, bv.y, bv.z, bv.w};
            float ad[4], aa[4];
#pragma unroll
            for (int i = 0; i < 4; ++i) {
                ad[i] = CPs[(i0 + i) * 64 + q];
                aa[i] = Ms[(i0 + i) * 64 + q];
            }
#pragma unroll
            for (int i = 0; i < 4; ++i)
#pragma unroll
                for (int j = 0; j < 4; ++j) {
                    accd[i][j] += ad[i] * bb[j];
                    acca[i][j] += aa[i] * bb[j];
                }
        }
        __syncthreads();   // Ms readers done before Tas overwrite
#pragma unroll
        for (int i = 0; i < 4; ++i)
#pragma unroll
            for (int j = 0; j < 4; ++j) {
                Tds[(i0 + i) * 64 + j0 + j] = accd[i][j];
                Tas[(i0 + i) * 64 + j0 + j] = acca[i][j];
            }
    }
    __syncthreads();

    // (7) E[e][c^16] = q(c)*(2Td - Td*Ta)[e][c] -> @4096 (CPs dead)
    {
        const int e0 = ty * 4, c0 = tx * 4;
        float acc[4][4];
#pragma unroll
        for (int i = 0; i < 4; ++i)
#pragma unroll
            for (int j = 0; j < 4; ++j) acc[i][j] = 0.f;
        for (int q = 0; q < 64; ++q) {
            const float4 bv = *reinterpret_cast<const float4*>(&Tas[q * 64 + c0]);
            const float bb[4] = {bv.x, bv.y, bv.z, bv.w};
            float a[4];
#pragma unroll
            for (int i = 0; i < 4; ++i) a[i] = Tds[(e0 + i) * 64 + q];
#pragma unroll
            for (int i = 0; i < 4; ++i)
#pragma unroll
                for (int j = 0; j < 4; ++j) acc[i][j] += a[i] * bb[j];
        }
        float qv[4];
#pragma unroll
        for (int j = 0; j < 4; ++j) qv[j] = qval(coeff, coeff_l, b, c0 + j);
#pragma unroll
        for (int i = 0; i < 4; ++i) {
            float4 o;
            o.x = qv[0] * (2.f * Tds[(e0 + i) * 64 + c0 + 0] - acc[i][0]);
            o.y = qv[1] * (2.f * Tds[(e0 + i) * 64 + c0 + 1] - acc[i][1]);
            o.z = qv[2] * (2.f * Tds[(e0 + i) * 64 + c0 + 2] - acc[i][2]);
            o.w = qv[3] * (2.f * Tds[(e0 + i) * 64 + c0 + 3] - acc[i][3]);
            *reinterpret_cast<float4*>(&Es[(e0 + i) * 64 + (c0 ^ 16)]) = o;
        }
    }
    __syncthreads();

    // (8) SE chunks (hc=0..7): Ss -> SEs -> fragment emission. Es stays live.
    for (int hc = 0; hc < 8; ++hc) {
        for (int idx = t; idx < 4096; idx += 256) {
            const int hl_ = idx >> 6, e = idx & 63;
            Ss[hl_ * 66 + e] = Sval(l, r, ll, rl, hc * 64 + hl_, e);
        }
        __syncthreads();
        {
            const int h = t >> 2;
            const int mg = (t & 3) * 16;
            float acc[16];
#pragma unroll
            for (int q = 0; q < 16; ++q) acc[q] = 0.f;
#pragma unroll 4
            for (int e = 0; e < 64; ++e) {
                const float s = Ss[h * 66 + e];
                const float* Er = Es + e * 64 + mg;
#pragma unroll
                for (int q = 0; q < 16; ++q) acc[q] += s * Er[q];
            }
#pragma unroll
            for (int q = 0; q < 16; ++q) SEs[h * 65 + mg + q] = acc[q];
        }
        __syncthreads();
        unsigned short* outp = SEf + (size_t)b * 65536 + hc * 8192;
#pragma unroll
        for (int it = 0; it < 4; ++it) {
            const int widx0 = it * 2048 + t * 8;
            const int fl = widx0 >> 10;
            const int hl = (widx0 >> 9) & 1;
            const int lx = (widx0 >> 3) & 63;
            const int m = (fl & 3) * 16 + (lx & 15);
            const int hb = (fl >> 2) * 32 + ((lx >> 4) & 3) * 8;
            unsigned short wv[8];
#pragma unroll
            for (int i = 0; i < 8; ++i) {
                short hh, ss;
                bf16_split(SEs[(hb + i) * 65 + m], hh, ss);
                wv[i] = hl ? (unsigned short)ss : (unsigned short)hh;
            }
            uint4 pk;
            pk.x = (unsigned)wv[0] | ((unsigned)wv[1] << 16);
            pk.y = (unsigned)wv[2] | ((unsigned)wv[3] << 16);
            pk.z = (unsigned)wv[4] | ((unsigned)wv[5] << 16);
            pk.w = (unsigned)wv[6] | ((unsigned)wv[7] << 16);
            *reinterpret_cast<uint4*>(outp + widx0) = pk;
        }
        __syncthreads();  // SEs/Ss readers done before next chunk's writes
    }
}

// out = x + ((x * SE_b) * S^T) via split-bf16 MFMA, LDS-staged x (hi/lo),
// XPAD=524. Byte-identical to R13. grid (128, 8), 4 waves.
__global__ __launch_bounds__(256, 2) void k_mix(const float* x,
                                                const unsigned short* SEf,
                                                const unsigned short* Sf,
                                                float* out) {
    __shared__ unsigned short xh[32 * XPAD];
    __shared__ unsigned short xl[32 * XPAD];
    __shared__ float Zs[32 * 68];
    const int b = blockIdx.y;
    const int r0 = blockIdx.x * 32;
    const int t = threadIdx.x;
    const int w = t >> 6;
    const int l = t & 63;
    const int lm = l & 15;
    const int lk = (l >> 4) * 8;
    const int rw = w & 1, cw = w >> 1;
    const float* xb = x + (size_t)b * N_ * F_;
    float* outb = out + (size_t)b * N_ * F_;
    const unsigned short* sef = SEf + (size_t)b * 65536;

#pragma unroll 4
    for (int it = 0; it < 16; ++it) {
        const int idx = it * 256 + t;
        const int row = idx >> 7, c4 = (idx & 127) * 4;
        const float4 v = *reinterpret_cast<const float4*>(
            xb + (size_t)(r0 + row) * F_ + c4);
        ushort4 hs, ls;
        short hh, ss;
        bf16_split(v.x, hh, ss); hs.x = (unsigned short)hh; ls.x = (unsigned short)ss;
        bf16_split(v.y, hh, ss); hs.y = (unsigned short)hh; ls.y = (unsigned short)ss;
        bf16_split(v.z, hh, ss); hs.z = (unsigned short)hh; ls.z = (unsigned short)ss;
        bf16_split(v.w, hh, ss); hs.w = (unsigned short)hh; ls.w = (unsigned short)ss;
        *reinterpret_cast<ushort4*>(&xh[row * XPAD + c4]) = hs;
        *reinterpret_cast<ushort4*>(&xl[row * XPAD + c4]) = ls;
    }
    __syncthreads();

    f32x4 ahh0 = {0.f, 0.f, 0.f, 0.f}, alh0 = ahh0, ahl0 = ahh0;
    f32x4 ahh1 = ahh0, alh1 = ahh0, ahl1 = ahh0;
    const unsigned short* xhr = xh + (16 * rw + lm) * XPAD;
    const unsigned short* xlr = xl + (16 * rw + lm) * XPAD;
#pragma unroll 4
    for (int kk = 0; kk < 16; ++kk) {
        const int k0 = kk * 32 + lk;
        const bf16x8 ah = *reinterpret_cast<const bf16x8*>(xhr + k0);
        const bf16x8 al = *reinterpret_cast<const bf16x8*>(xlr + k0);
        const int o0 = (kk * 4 + 2 * cw) * 1024 + l * 8;
        const bf16x8 bh0 = *reinterpret_cast<const bf16x8*>(sef + o0);
        const bf16x8 bl0 = *reinterpret_cast<const bf16x8*>(sef + o0 + 512);
        const bf16x8 bh1 = *reinterpret_cast<const bf16x8*>(sef + o0 + 1024);
        const bf16x8 bl1 = *reinterpret_cast<const bf16x8*>(sef + o0 + 1536);
        ahh0 = __builtin_amdgcn_mfma_f32_16x16x32_bf16(ah, bh0, ahh0, 0, 0, 0);
        alh0 = __builtin_amdgcn_mfma_f32_16x16x32_bf16(al, bh0, alh0, 0, 0, 0);
        ahl0 = __builtin_amdgcn_mfma_f32_16x16x32_bf16(ah, bl0, ahl0, 0, 0, 0);
        ahh1 = __builtin_amdgcn_mfma_f32_16x16x32_bf16(ah, bh1, ahh1, 0, 0, 0);
        alh1 = __builtin_amdgcn_mfma_f32_16x16x32_bf16(al, bh1, alh1, 0, 0, 0);
        ahl1 = __builtin_amdgcn_mfma_f32_16x16x32_bf16(ah, bl1, ahl1, 0, 0, 0);
    }
#pragma unroll
    for (int r = 0; r < 4; ++r) {
        const int zr = (16 * rw + (l >> 4) * 4 + r) * 68 + 32 * cw;
        Zs[zr + lm] = ahh0[r] + alh0[r] + ahl0[r];
        Zs[zr + 16 + lm] = ahh1[r] + alh1[r] + ahl1[r];
    }
    __syncthreads();

    bf16x8 zh0, zl0, zh1, zl1;
    {
        const float* zrow = &Zs[(16 * rw + lm) * 68];
#pragma unroll
        for (int i = 0; i < 8; ++i) {
            short hh, ss;
            bf16_split(zrow[lk + i], hh, ss);
            zh0[i] = hh; zl0[i] = ss;
            bf16_split(zrow[32 + lk + i], hh, ss);
            zh1[i] = hh; zl1[i] = ss;
        }
    }
    const int lrow0 = 16 * rw + (l >> 4) * 4;
    const int orow0 = r0 + lrow0;
#pragma unroll 2
    for (int j2 = 0; j2 < 16; ++j2) {
        const int ht = cw * 16 + j2;
        const int h0 = ht * 16 + lm;
        f32x4 ca = {0.f, 0.f, 0.f, 0.f};
        f32x4 cb;
#pragma unroll
        for (int r = 0; r < 4; ++r) {
            const int la = (lrow0 + r) * XPAD + h0;
            cb[r] = b2f(xh[la]) + b2f(xl[la]);
        }
        const int fb = ht * 2048 + l * 8;
        const bf16x8 bh0 = *reinterpret_cast<const bf16x8*>(Sf + fb);
        const bf16x8 bl0 = *reinterpret_cast<const bf16x8*>(Sf + fb + 512);
        const bf16x8 bh1 = *reinterpret_cast<const bf16x8*>(Sf + fb + 1024);
        const bf16x8 bl1 = *reinterpret_cast<const bf16x8*>(Sf + fb + 1536);
        ca = __builtin_amdgcn_mfma_f32_16x16x32_bf16(zh0, bh0, ca, 0, 0, 0);
        ca = __builtin_amdgcn_mfma_f32_16x16x32_bf16(zl0, bh0, ca, 0, 0, 0);
        ca = __builtin_amdgcn_mfma_f32_16x16x32_bf16(zh0, bl0, ca, 0, 0, 0);
        cb = __builtin_amdgcn_mfma_f32_16x16x32_bf16(zh1, bh1, cb, 0, 0, 0);
        cb = __builtin_amdgcn_mfma_f32_16x16x32_bf16(zl1, bh1, cb, 0, 0, 0);
        cb = __builtin_amdgcn_mfma_f32_16x16x32_bf16(zh1, bl1, cb, 0, 0, 0);
#pragma unroll
        for (int r = 0; r < 4; ++r)
            outb[(size_t)(orow0 + r) * F_ + h0] = ca[r] + cb[r];
    }
}

extern "C" void kernel_launch(void* const* d_in, const int* in_sizes, int n_in,
                              void* d_out, int out_size, void* d_ws, size_t ws_size,
                              hipStream_t stream) {
    (void)in_sizes; (void)n_in; (void)out_size; (void)ws_size;
    const float* x       = (const float*)d_in[0];
    const float* coeff   = (const float*)d_in[1];
    const float* gate    = (const float*)d_in[2];
    const float* coeff_l = (const float*)d_in[3];
    const float* gate_l  = (const float*)d_in[4];
    const float* comm    = (const float*)d_in[5];
    const float* l       = (const float*)d_in[6];
    const float* r       = (const float*)d_in[7];
    const float* ll      = (const float*)d_in[8];
    const float* rl      = (const float*)d_in[9];

    char* wsb = (char*)d_ws;
    float* GS   = (float*)(wsb);                              // 4096 f       @0
    unsigned short* SEf = (unsigned short*)(wsb + 147456);    // 8*65536 u16  @144K (1MB)
    unsigned short* Sf  = (unsigned short*)(wsb + 1196032);   // 65536 u16    @1168K (128K)
    float* out = (float*)d_out;

    k_prep<<<dim3(64), dim3(256), 0, stream>>>(l, r, ll, rl, GS, Sf);
    k_solve<<<dim3(8), dim3(256), 0, stream>>>(coeff, gate, coeff_l, gate_l, comm, GS,
                                               l, r, ll, rl, SEf);
    k_mix<<<dim3(128, 8), dim3(256), 0, stream>>>(x, SEf, Sf, out);
}